// Round 1
// baseline (272.218 us; speedup 1.0000x reference)
//
#include <hip/hip_runtime.h>
#include <math.h>

// SSIM loss, fused: separable 11x11 Gaussian depthwise conv (5 channels of
// statistics) + SSIM map + global mean, in one tiled kernel.
// Inputs: img1, img2  float32 [16,3,512,512].  Output: scalar float32.

#define TS     32              // output tile (TS x TS)
#define HALO   5               // (11-1)/2
#define KSZ    11
#define LT     (TS + 2*HALO)   // 42 = loaded tile
#define LSTR   (LT + 2)        // 44 = LDS row stride for inputs
#define IMG    512
#define NPLANES (16*3)
#define NPIX   (16*3*512*512)

__device__ __forceinline__ void get_weights(float* w) {
    float s = 0.f;
#pragma unroll
    for (int i = 0; i < KSZ; ++i) {
        float d = (float)(i - HALO);
        w[i] = expf(-(d * d) / (2.0f * 1.5f * 1.5f));
        s += w[i];
    }
    float inv = 1.0f / s;
#pragma unroll
    for (int i = 0; i < KSZ; ++i) w[i] *= inv;
}

__global__ void __launch_bounds__(256)
ssim_tile_kernel(const float* __restrict__ img1,
                 const float* __restrict__ img2,
                 float* __restrict__ acc)
{
    __shared__ float s1[LT][LSTR];
    __shared__ float s2[LT][LSTR];
    __shared__ float h[5][LT][TS];   // mu1,mu2,x1x1,x2x2,x1x2 after horiz pass
    __shared__ float wsum[4];

    float w[KSZ];
    get_weights(w);

    const int tid   = threadIdx.x;
    const int gx0   = blockIdx.x * TS - HALO;
    const int gy0   = blockIdx.y * TS - HALO;
    const int plane = blockIdx.z;

    const float* __restrict__ p1 = img1 + (size_t)plane * IMG * IMG;
    const float* __restrict__ p2 = img2 + (size_t)plane * IMG * IMG;

    // ---- load 42x42 halo tiles (zero padding outside the image) ----
    for (int i = tid; i < LT * LT; i += 256) {
        int r = i / LT;
        int c = i - r * LT;
        int gy = gy0 + r, gx = gx0 + c;
        float v1 = 0.f, v2 = 0.f;
        if ((unsigned)gy < IMG && (unsigned)gx < IMG) {
            size_t off = (size_t)gy * IMG + gx;
            v1 = p1[off];
            v2 = p2[off];
        }
        s1[r][c] = v1;
        s2[r][c] = v2;
    }
    __syncthreads();

    // ---- horizontal 11-tap pass: LT rows x TS cols, 5 statistics ----
    for (int i = tid; i < LT * TS; i += 256) {
        int r = i >> 5;        // / TS
        int c = i & (TS - 1);  // % TS
        float m1 = 0.f, m2 = 0.f, a11 = 0.f, a22 = 0.f, a12 = 0.f;
#pragma unroll
        for (int k = 0; k < KSZ; ++k) {
            float wk = w[k];
            float v1 = s1[r][c + k];
            float v2 = s2[r][c + k];
            m1  += wk * v1;
            m2  += wk * v2;
            a11 += wk * v1 * v1;
            a22 += wk * v2 * v2;
            a12 += wk * v1 * v2;
        }
        h[0][r][c] = m1;
        h[1][r][c] = m2;
        h[2][r][c] = a11;
        h[3][r][c] = a22;
        h[4][r][c] = a12;
    }
    __syncthreads();

    // ---- vertical 11-tap pass + SSIM map, accumulate locally ----
    const float C1 = 0.01f * 0.01f;
    const float C2 = 0.03f * 0.03f;
    float local = 0.f;
    for (int i = tid; i < TS * TS; i += 256) {
        int r = i >> 5;
        int c = i & (TS - 1);
        float mu1 = 0.f, mu2 = 0.f, v11 = 0.f, v22 = 0.f, v12 = 0.f;
#pragma unroll
        for (int k = 0; k < KSZ; ++k) {
            float wk = w[k];
            mu1 += wk * h[0][r + k][c];
            mu2 += wk * h[1][r + k][c];
            v11 += wk * h[2][r + k][c];
            v22 += wk * h[3][r + k][c];
            v12 += wk * h[4][r + k][c];
        }
        float mu1sq = mu1 * mu1;
        float mu2sq = mu2 * mu2;
        float mu12  = mu1 * mu2;
        float sig1  = v11 - mu1sq;
        float sig2  = v22 - mu2sq;
        float sig12 = v12 - mu12;
        float num = (2.f * mu12 + C1) * (2.f * sig12 + C2);
        float den = (mu1sq + mu2sq + C1) * (sig1 + sig2 + C2);
        local += num / den;
    }

    // ---- block reduction: wave shuffle then LDS ----
#pragma unroll
    for (int off = 32; off > 0; off >>= 1)
        local += __shfl_down(local, off, 64);
    if ((tid & 63) == 0) wsum[tid >> 6] = local;
    __syncthreads();
    if (tid == 0) {
        float t = wsum[0] + wsum[1] + wsum[2] + wsum[3];
        atomicAdd(acc, t);
    }
}

__global__ void zero_acc_kernel(float* acc) {
    if (threadIdx.x == 0) acc[0] = 0.f;
}

__global__ void finalize_kernel(const float* __restrict__ acc,
                                float* __restrict__ out) {
    if (threadIdx.x == 0)
        out[0] = 1.0f - acc[0] * (1.0f / (float)NPIX);
}

extern "C" void kernel_launch(void* const* d_in, const int* in_sizes, int n_in,
                              void* d_out, int out_size, void* d_ws, size_t ws_size,
                              hipStream_t stream) {
    const float* img1 = (const float*)d_in[0];
    const float* img2 = (const float*)d_in[1];
    float* out = (float*)d_out;
    float* acc = (float*)d_ws;   // 1 float accumulator in workspace

    zero_acc_kernel<<<1, 64, 0, stream>>>(acc);
    dim3 grid(IMG / TS, IMG / TS, NPLANES);
    ssim_tile_kernel<<<grid, 256, 0, stream>>>(img1, img2, acc);
    finalize_kernel<<<1, 64, 0, stream>>>(acc, out);
}